// Round 4
// baseline (58442.499 us; speedup 1.0000x reference)
//
#include <hip/hip_runtime.h>

// Problem constants
#define Bc   64
#define Tc   512
#define NINc 256
#define Hc   512
#define NOUTc 256
#define NBLK 256
#define NTHR 1024
#define NWAVE 16

__device__ __forceinline__ double dsig(double x) { return 1.0 / (1.0 + exp(-x)); }

// ---- flag-array grid barrier: one release-store per block, parallel spin-reads ----
__device__ __forceinline__ void bar_signal(unsigned* __restrict__ flags, unsigned ep) {
  __syncthreads();  // all block work done; stores at L2 (vmcnt0) before release
  if (threadIdx.x == 0)
    __hip_atomic_store(&flags[blockIdx.x], ep, __ATOMIC_RELEASE, __HIP_MEMORY_SCOPE_AGENT);
}

__device__ __forceinline__ void bar_wait(unsigned* __restrict__ flags, unsigned ep) {
  if (threadIdx.x < 64) {
    const int l = threadIdx.x;
    for (;;) {
      bool ok = true;
#pragma unroll
      for (int i = 0; i < NBLK / 64; ++i) {
        unsigned v = __hip_atomic_load(&flags[l + i * 64], __ATOMIC_RELAXED,
                                       __HIP_MEMORY_SCOPE_AGENT);
        ok &= (v >= ep);
      }
      if (__all(ok)) break;
      __builtin_amdgcn_s_sleep(1);
    }
  }
  __syncthreads();
  __builtin_amdgcn_fence(__ATOMIC_ACQUIRE, "agent");  // invalidate, no writeback
}

// 8-row dot chunk, A strided by Bc floats per k (activations in [K][B] layout), f64 acc
__device__ __forceinline__ void dot8_sb(const float* __restrict__ A,
                                        const float* __restrict__ W,
                                        const int wstride, const int nk,
                                        double* __restrict__ acc) {
#pragma unroll 2
  for (int k = 0; k < nk; k += 4) {
    double a0 = (double)A[(k + 0) * Bc];
    double a1 = (double)A[(k + 1) * Bc];
    double a2 = (double)A[(k + 2) * Bc];
    double a3 = (double)A[(k + 3) * Bc];
#pragma unroll
    for (int r = 0; r < 8; ++r) {
      float4 w = *(const float4*)(W + r * wstride + k);
      acc[r] = fma(a0, (double)w.x, acc[r]);
      acc[r] = fma(a1, (double)w.y, acc[r]);
      acc[r] = fma(a2, (double)w.z, acc[r]);
      acc[r] = fma(a3, (double)w.w, acc[r]);
    }
  }
}

// Same but A contiguous in k (raw x row)
__device__ __forceinline__ void dot8_sc(const float* __restrict__ A,
                                        const float* __restrict__ W,
                                        const int wstride, const int nk,
                                        double* __restrict__ acc) {
#pragma unroll 2
  for (int k = 0; k < nk; k += 4) {
    float4 av = *(const float4*)(A + k);
#pragma unroll
    for (int r = 0; r < 8; ++r) {
      float4 w = *(const float4*)(W + r * wstride + k);
      acc[r] = fma((double)av.x, (double)w.x, acc[r]);
      acc[r] = fma((double)av.y, (double)w.y, acc[r]);
      acc[r] = fma((double)av.z, (double)w.z, acc[r]);
      acc[r] = fma((double)av.w, (double)w.w, acc[r]);
    }
  }
}

__device__ __forceinline__ void write_plane(float* __restrict__ pb,
                                            const double* __restrict__ acc,
                                            int kg, int b) {
#pragma unroll
  for (int r = 0; r < 8; ++r) pb[(kg * 8 + r) * 64 + b] = (float)acc[r];
}

__device__ __forceinline__ double sum_planes(const float* __restrict__ pb,
                                             int r, int b) {
  double s = 0.0;
#pragma unroll
  for (int p = 0; p < NWAVE; ++p) s += (double)pb[(p * 8 + r) * 64 + b];
  return s;
}

__device__ __forceinline__ float lstm_cell(const float* __restrict__ pb,
                                           const double* __restrict__ bias,
                                           int r0, int b, double* c) {
  double gi = sum_planes(pb, r0 + 0, b) + bias[r0 + 0];
  double gf = sum_planes(pb, r0 + 1, b) + bias[r0 + 1];
  double gg = sum_planes(pb, r0 + 2, b) + bias[r0 + 2];
  double go = sum_planes(pb, r0 + 3, b) + bias[r0 + 3];
  double cn = dsig(gf) * (*c) + dsig(gi) * tanh(gg);
  *c = cn;
  return (float)(dsig(go) * tanh(cn));
}

extern "C" __global__ __launch_bounds__(NTHR, 1)
void lstm_seq_kernel(const float* __restrict__ x,      // [B,T,NIN]
                     const float* __restrict__ h0in,   // [L,B,H]
                     const float* __restrict__ c0in,   // [L,B,H]
                     const float* __restrict__ Wih0,   // [4H,NIN]
                     const float* __restrict__ Wih1,   // [4H,H]
                     const float* __restrict__ Whh,    // [L,4H,H]
                     const float* __restrict__ bih,    // [L,4H]
                     const float* __restrict__ bhh,    // [L,4H]
                     const float* __restrict__ Wemb,   // [NOUT,H]
                     const float* __restrict__ bemb,   // [NOUT]
                     const unsigned char* __restrict__ uprev, // [T] bool (or int32)
                     float* __restrict__ out,          // [B,T,NOUT]
                     float* __restrict__ ws) {
  __shared__ __align__(16) float wl0[8 * 768];    // [r][ W_ih0(256) | W_hh0(512) ]
  __shared__ __align__(16) float wl1[8 * 1024];   // [r][ W_ih1(512) | W_hh1(512) ]
  __shared__ __align__(16) float whd[512];        // W_emb row `blk`
  __shared__ __align__(16) float pbuf[NWAVE * 8 * 64];
  __shared__ double biasesD[2][8];
  __shared__ double bembs;
  __shared__ int up_mode;

  const int tid = threadIdx.x;
  const int blk = blockIdx.x;
  const int b   = tid & 63;
  const int kg  = tid >> 6;   // wave index = K-group (0..15)
  const int j0  = blk * 2;

  unsigned* flags = (unsigned*)ws;             // 256 u32, zeroed by host memset
  float* hbuf = ws + 256;                      // [2 parity][L][H][B]
  float* outT = hbuf + 2 * 2 * Hc * Bc;        // [NOUT][B]

  // ---- detect use_prev dtype ----
  if (tid == 0) up_mode = 1;
  __syncthreads();
  {
    int bad = 0;
    for (int idx = tid; idx < Tc; idx += NTHR)
      if ((idx & 3) && uprev[idx]) bad = 1;
    if (bad) up_mode = 0;
  }

  // ---- load weights into LDS ----
  for (int r = 0; r < 8; ++r) {
    const int u = r >> 2, g = r & 3;
    const int row = g * Hc + (j0 + u);
    const float* sA = Wih0 + (size_t)row * NINc;
    const float* sB = Whh  + (size_t)row * Hc;
    const float* sC = Wih1 + (size_t)row * Hc;
    const float* sD = Whh  + (size_t)(4 * Hc) * Hc + (size_t)row * Hc;
    for (int i = tid; i < NINc; i += NTHR) wl0[r * 768 + i] = sA[i];
    for (int i = tid; i < Hc;   i += NTHR) wl0[r * 768 + NINc + i] = sB[i];
    for (int i = tid; i < Hc;   i += NTHR) wl1[r * 1024 + i] = sC[i];
    for (int i = tid; i < Hc;   i += NTHR) wl1[r * 1024 + Hc + i] = sD[i];
    if (tid == 0) {
      biasesD[0][r] = (double)bih[row] + (double)bhh[row];
      biasesD[1][r] = (double)bih[4 * Hc + row] + (double)bhh[4 * Hc + row];
    }
  }
  for (int i = tid; i < Hc; i += NTHR) whd[i] = Wemb[(size_t)blk * Hc + i];
  if (tid == 0) bembs = (double)bemb[blk];

  // ---- init h (parity 0) transposed to [L][H][B] ----
  for (int idx = blk * NTHR + tid; idx < 2 * Hc * Bc; idx += NBLK * NTHR) {
    const int l   = idx / (Hc * Bc);
    const int rem = idx - l * (Hc * Bc);
    const int j   = rem >> 6;
    const int bb  = rem & 63;
    hbuf[idx] = h0in[((size_t)l * Bc + bb) * Hc + j];
  }

  // ---- cell state (f64) in registers of threads 0..127 ----
  double c0r = 0.0, c1r = 0.0;
  const int cu = tid >> 6;
  if (tid < 128) {
    const int j = j0 + cu;
    c0r = (double)c0in[((size_t)0 * Bc + b) * Hc + j];
    c1r = (double)c0in[((size_t)1 * Bc + b) * Hc + j];
  }
  __syncthreads();
  const int upm = up_mode;
  const int* uprev32 = (const int*)uprev;
#define UPAT(tt) (upm ? (uprev32[tt] != 0) : (uprev[tt] != 0))

  unsigned ep = 0;
  bar_signal(flags, ++ep);
  bar_wait(flags, ep);

  // ---- pre-loop: L0[0] pre-activation (up[0] is false by construction) ----
  double accL0[8];
#pragma unroll
  for (int r = 0; r < 8; ++r) accL0[r] = 0.0;
  dot8_sc(x + ((size_t)b * Tc + 0) * NINc + kg * 16, &wl0[kg * 16], 768, 16, accL0);
  dot8_sb(hbuf + (kg * 32) * Bc + b, &wl0[NINc + kg * 32], 768, 32, accL0);

  for (int t = 0; t < Tc; ++t) {
    const int p = t & 1;
    const float* hRd = hbuf + p * (2 * Hc * Bc);
    float* hWr = hbuf + (p ^ 1) * (2 * Hc * Bc);
    const bool upn = (t + 1 < Tc) && UPAT(t + 1);

    // ---- phase a: finish L0[t] (out-part only when feedback) ----
    if (t > 0 && UPAT(t))
      dot8_sb(outT + (kg * 16) * Bc + b, &wl0[kg * 16], 768, 16, accL0);
    write_plane(pbuf, accL0, kg, b);
    __syncthreads();
    if (tid < 128) {
      float hn = lstm_cell(pbuf, biasesD[0], cu * 4, b, &c0r);
      hWr[(j0 + cu) * Bc + b] = hn;
    }
    bar_signal(flags, ++ep);

    // ---- phase b (hidden behind barrier): L1 recurrent part, h1[t-1] ----
    double acc[8];
#pragma unroll
    for (int r = 0; r < 8; ++r) acc[r] = 0.0;
    dot8_sb(hRd + Hc * Bc + (kg * 32) * Bc + b, &wl1[Hc + kg * 32], 1024, 32, acc);

    bar_wait(flags, ep);   // h0[t] now visible

    // ---- phase c: L1 dependent part ----
    dot8_sb(hWr + (kg * 32) * Bc + b, &wl1[kg * 32], 1024, 32, acc);
    write_plane(pbuf, acc, kg, b);
    __syncthreads();
    if (tid < 128) {
      float hn = lstm_cell(pbuf, biasesD[1], cu * 4, b, &c1r);
      hWr[Hc * Bc + (j0 + cu) * Bc + b] = hn;
    }
    bar_signal(flags, ++ep);

    // ---- phase d (hidden behind barrier): precompute L0[t+1] indep parts ----
#pragma unroll
    for (int r = 0; r < 8; ++r) accL0[r] = 0.0;
    if (t + 1 < Tc) {
      if (!upn)
        dot8_sc(x + ((size_t)b * Tc + (t + 1)) * NINc + kg * 16, &wl0[kg * 16], 768, 16, accL0);
      dot8_sb(hWr + (kg * 32) * Bc + b, &wl0[NINc + kg * 32], 768, 32, accL0); // W_hh0 @ h0[t]
    }

    bar_wait(flags, ep);   // h1[t] now visible

    // ---- phase e: head (row n = blk) ----
    {
      const float* Ah = hWr + Hc * Bc + (kg * 32) * Bc + b;
      const float* Wh = &whd[kg * 32];
      double h0a = 0.0, h1a = 0.0, h2a = 0.0, h3a = 0.0;
#pragma unroll 2
      for (int k = 0; k < 32; k += 4) {
        float4 w = *(const float4*)(Wh + k);
        h0a = fma((double)Ah[(k + 0) * Bc], (double)w.x, h0a);
        h1a = fma((double)Ah[(k + 1) * Bc], (double)w.y, h1a);
        h2a = fma((double)Ah[(k + 2) * Bc], (double)w.z, h2a);
        h3a = fma((double)Ah[(k + 3) * Bc], (double)w.w, h3a);
      }
      pbuf[kg * 64 + b] = (float)((h0a + h1a) + (h2a + h3a));
    }
    __syncthreads();
    if (tid < 64) {
      double s = bembs;
#pragma unroll
      for (int pl = 0; pl < NWAVE; ++pl) s += (double)pbuf[pl * 64 + b];
      float o = (float)tanh(s);
      outT[blk * Bc + b] = o;                          // feedback buffer [NOUT][B]
      out[((size_t)b * Tc + t) * NOUTc + blk] = o;     // final output [B,T,NOUT]
    }
    if (upn) {
      bar_signal(flags, ++ep);   // publish out[t]
      bar_wait(flags, ep);
    } else if (t + 1 < Tc) {
      __syncthreads();           // pbuf reuse guard
    }
  }
}

extern "C" void kernel_launch(void* const* d_in, const int* in_sizes, int n_in,
                              void* d_out, int out_size, void* d_ws, size_t ws_size,
                              hipStream_t stream) {
  const float* x    = (const float*)d_in[0];
  const float* h0   = (const float*)d_in[1];
  const float* c0   = (const float*)d_in[2];
  const float* Wih0 = (const float*)d_in[3];
  const float* Wih1 = (const float*)d_in[4];
  const float* Whh  = (const float*)d_in[5];
  const float* bih  = (const float*)d_in[6];
  const float* bhh  = (const float*)d_in[7];
  const float* Wemb = (const float*)d_in[8];
  const float* bemb = (const float*)d_in[9];
  const unsigned char* uprev = (const unsigned char*)d_in[10];
  float* out = (float*)d_out;
  float* ws  = (float*)d_ws;

  // zero the flag array (first 1 KiB of ws) every call (inside graph, so every replay)
  hipMemsetAsync(d_ws, 0, 1024, stream);

  void* args[] = {(void*)&x, (void*)&h0, (void*)&c0, (void*)&Wih0, (void*)&Wih1,
                  (void*)&Whh, (void*)&bih, (void*)&bhh, (void*)&Wemb, (void*)&bemb,
                  (void*)&uprev, (void*)&out, (void*)&ws};
  hipLaunchCooperativeKernel((void*)lstm_seq_kernel, dim3(NBLK), dim3(NTHR),
                             args, 0, stream);
}

// Round 5
// 53439.465 us; speedup vs baseline: 1.0936x; 1.0936x over previous
//
#include <hip/hip_runtime.h>

// Problem constants
#define Bc   64
#define Tc   512
#define NINc 256
#define Hc   512
#define NOUTc 256
#define NBLK 256
#define NTHR 1024
#define NWAVE 16

__device__ __forceinline__ double dsig(double x) { return 1.0 / (1.0 + exp(-x)); }

// ---- agent-coherent scalar accesses (bypass L1/L2, meet at L3/fabric) ----
__device__ __forceinline__ float ldg1(const float* p) {
  return __hip_atomic_load(p, __ATOMIC_RELAXED, __HIP_MEMORY_SCOPE_AGENT);
}
__device__ __forceinline__ void stg1(float* p, float v) {
  __hip_atomic_store(p, v, __ATOMIC_RELAXED, __HIP_MEMORY_SCOPE_AGENT);
}

// ---- flag-array grid barrier, no cache maintenance ----
// signal: __syncthreads() drains vmcnt(0) per wave (all sc1 stores ACKed at the
// coherence point) before tid0's flag store issues. No wbl2 needed.
__device__ __forceinline__ void bar_signal(unsigned* __restrict__ flags, unsigned ep) {
  __syncthreads();
  asm volatile("" ::: "memory");
  if (threadIdx.x == 0)
    __hip_atomic_store(&flags[blockIdx.x], ep, __ATOMIC_RELAXED, __HIP_MEMORY_SCOPE_AGENT);
}
// wait: wave 0 polls all flags; data plane is sc1-coherent so no invalidate.
__device__ __forceinline__ void bar_wait(unsigned* __restrict__ flags, unsigned ep) {
  if (threadIdx.x < 64) {
    for (;;) {
      bool ok = true;
#pragma unroll
      for (int i = 0; i < NBLK / 64; ++i) {
        unsigned v = __hip_atomic_load(&flags[threadIdx.x + i * 64], __ATOMIC_RELAXED,
                                       __HIP_MEMORY_SCOPE_AGENT);
        ok &= (v >= ep);
      }
      if (__all(ok)) break;
      __builtin_amdgcn_s_sleep(2);
    }
  }
  asm volatile("" ::: "memory");
  __syncthreads();
}

// ---- 8-row dot chunk, A strided by Bc (activations, sc1 loads preloaded to regs) ----
// mixed precision: 4-term f32 fma groups summed into f64 accumulators
template<int NK>
__device__ __forceinline__ void dot8_a(const float* __restrict__ A,
                                       const float* __restrict__ W,
                                       const int wstride,
                                       double* __restrict__ acc) {
  float av[NK];
#pragma unroll
  for (int k = 0; k < NK; ++k) av[k] = ldg1(A + k * Bc);
#pragma unroll
  for (int kk = 0; kk < NK; kk += 4) {
#pragma unroll
    for (int r = 0; r < 8; ++r) {
      float4 w = *(const float4*)(W + r * wstride + kk);
      float p =  av[kk + 0] * w.x;
      p = fmaf(av[kk + 1], w.y, p);
      p = fmaf(av[kk + 2], w.z, p);
      p = fmaf(av[kk + 3], w.w, p);
      acc[r] += (double)p;
    }
  }
}

// Same but A contiguous and normally cached (the raw x input)
template<int NK>
__device__ __forceinline__ void dot8_x(const float* __restrict__ A,
                                       const float* __restrict__ W,
                                       const int wstride,
                                       double* __restrict__ acc) {
#pragma unroll
  for (int kk = 0; kk < NK; kk += 4) {
    float4 av = *(const float4*)(A + kk);
#pragma unroll
    for (int r = 0; r < 8; ++r) {
      float4 w = *(const float4*)(W + r * wstride + kk);
      float p =  av.x * w.x;
      p = fmaf(av.y, w.y, p);
      p = fmaf(av.z, w.z, p);
      p = fmaf(av.w, w.w, p);
      acc[r] += (double)p;
    }
  }
}

__device__ __forceinline__ void write_plane(float* __restrict__ pb,
                                            const double* __restrict__ acc,
                                            int kg, int b) {
#pragma unroll
  for (int r = 0; r < 8; ++r) pb[(kg * 8 + r) * 64 + b] = (float)acc[r];
}

__device__ __forceinline__ double sum_planes(const float* __restrict__ pb,
                                             int r, int b) {
  double s = 0.0;
#pragma unroll
  for (int p = 0; p < NWAVE; ++p) s += (double)pb[(p * 8 + r) * 64 + b];
  return s;
}

__device__ __forceinline__ float lstm_cell(const float* __restrict__ pb,
                                           const double* __restrict__ bias,
                                           int r0, int b, double* c) {
  double gi = sum_planes(pb, r0 + 0, b) + bias[r0 + 0];
  double gf = sum_planes(pb, r0 + 1, b) + bias[r0 + 1];
  double gg = sum_planes(pb, r0 + 2, b) + bias[r0 + 2];
  double go = sum_planes(pb, r0 + 3, b) + bias[r0 + 3];
  double cn = dsig(gf) * (*c) + dsig(gi) * tanh(gg);
  *c = cn;
  return (float)(dsig(go) * tanh(cn));
}

extern "C" __global__ __launch_bounds__(NTHR, 1)
void lstm_seq_kernel(const float* __restrict__ x,      // [B,T,NIN]
                     const float* __restrict__ h0in,   // [L,B,H]
                     const float* __restrict__ c0in,   // [L,B,H]
                     const float* __restrict__ Wih0,   // [4H,NIN]
                     const float* __restrict__ Wih1,   // [4H,H]
                     const float* __restrict__ Whh,    // [L,4H,H]
                     const float* __restrict__ bih,    // [L,4H]
                     const float* __restrict__ bhh,    // [L,4H]
                     const float* __restrict__ Wemb,   // [NOUT,H]
                     const float* __restrict__ bemb,   // [NOUT]
                     const unsigned char* __restrict__ uprev, // [T] bool (or int32)
                     float* __restrict__ out,          // [B,T,NOUT]
                     float* __restrict__ ws) {
  __shared__ __align__(16) float wl0[8 * 768];    // [r][ W_ih0(256) | W_hh0(512) ]
  __shared__ __align__(16) float wl1[8 * 1024];   // [r][ W_ih1(512) | W_hh1(512) ]
  __shared__ __align__(16) float whd[512];        // W_emb row `blk`
  __shared__ __align__(16) float pbuf[NWAVE * 8 * 64];
  __shared__ double biasesD[2][8];
  __shared__ double bembs;
  __shared__ int up_mode;

  const int tid = threadIdx.x;
  const int blk = blockIdx.x;
  const int b   = tid & 63;
  const int kg  = tid >> 6;   // wave index = K-group (0..15)
  const int j0  = blk * 2;

  unsigned* flags = (unsigned*)ws;             // 256 u32, zeroed by host memset
  float* hbuf = ws + 256;                      // [2 parity][L][H][B]
  float* outT = hbuf + 2 * 2 * Hc * Bc;        // [NOUT][B]

  // ---- detect use_prev dtype ----
  if (tid == 0) up_mode = 1;
  __syncthreads();
  {
    int bad = 0;
    for (int idx = tid; idx < Tc; idx += NTHR)
      if ((idx & 3) && uprev[idx]) bad = 1;
    if (bad) up_mode = 0;
  }

  // ---- load weights into LDS (normally cached reads; never invalidated) ----
  for (int r = 0; r < 8; ++r) {
    const int u = r >> 2, g = r & 3;
    const int row = g * Hc + (j0 + u);
    const float* sA = Wih0 + (size_t)row * NINc;
    const float* sB = Whh  + (size_t)row * Hc;
    const float* sC = Wih1 + (size_t)row * Hc;
    const float* sD = Whh  + (size_t)(4 * Hc) * Hc + (size_t)row * Hc;
    for (int i = tid; i < NINc; i += NTHR) wl0[r * 768 + i] = sA[i];
    for (int i = tid; i < Hc;   i += NTHR) wl0[r * 768 + NINc + i] = sB[i];
    for (int i = tid; i < Hc;   i += NTHR) wl1[r * 1024 + i] = sC[i];
    for (int i = tid; i < Hc;   i += NTHR) wl1[r * 1024 + Hc + i] = sD[i];
    if (tid == 0) {
      biasesD[0][r] = (double)bih[row] + (double)bhh[row];
      biasesD[1][r] = (double)bih[4 * Hc + row] + (double)bhh[4 * Hc + row];
    }
  }
  for (int i = tid; i < Hc; i += NTHR) whd[i] = Wemb[(size_t)blk * Hc + i];
  if (tid == 0) bembs = (double)bemb[blk];

  // ---- init h (parity 0) transposed to [L][H][B]; sc1 stores ----
  for (int idx = blk * NTHR + tid; idx < 2 * Hc * Bc; idx += NBLK * NTHR) {
    const int l   = idx / (Hc * Bc);
    const int rem = idx - l * (Hc * Bc);
    const int j   = rem >> 6;
    const int bb  = rem & 63;
    stg1(&hbuf[idx], h0in[((size_t)l * Bc + bb) * Hc + j]);
  }

  // ---- cell state (f64) in registers of threads 0..127 ----
  double c0r = 0.0, c1r = 0.0;
  const int cu = tid >> 6;
  if (tid < 128) {
    const int j = j0 + cu;
    c0r = (double)c0in[((size_t)0 * Bc + b) * Hc + j];
    c1r = (double)c0in[((size_t)1 * Bc + b) * Hc + j];
  }
  __syncthreads();
  const int upm = up_mode;
  const int* uprev32 = (const int*)uprev;
#define UPAT(tt) (upm ? (uprev32[tt] != 0) : (uprev[tt] != 0))

  unsigned ep = 0;
  bar_signal(flags, ++ep);
  bar_wait(flags, ep);

  // ---- pre-loop: L0[0] pre-activation (up[0] is false by construction) ----
  double accL0[8];
#pragma unroll
  for (int r = 0; r < 8; ++r) accL0[r] = 0.0;
  dot8_x<16>(x + ((size_t)b * Tc + 0) * NINc + kg * 16, &wl0[kg * 16], 768, accL0);
  dot8_a<32>(hbuf + (kg * 32) * Bc + b, &wl0[NINc + kg * 32], 768, accL0);

  for (int t = 0; t < Tc; ++t) {
    const int p = t & 1;
    const float* hRd = hbuf + p * (2 * Hc * Bc);
    float* hWr = hbuf + (p ^ 1) * (2 * Hc * Bc);
    const bool upn = (t + 1 < Tc) && UPAT(t + 1);

    // ---- phase a: finish L0[t] (out-part only when feedback) ----
    if (t > 0 && UPAT(t))
      dot8_a<16>(outT + (kg * 16) * Bc + b, &wl0[kg * 16], 768, accL0);
    write_plane(pbuf, accL0, kg, b);
    __syncthreads();
    if (tid < 128) {
      float hn = lstm_cell(pbuf, biasesD[0], cu * 4, b, &c0r);
      stg1(&hWr[(j0 + cu) * Bc + b], hn);
    }
    bar_signal(flags, ++ep);

    // ---- phase b (hidden behind barrier): L1 recurrent part, h1[t-1] ----
    double acc[8];
#pragma unroll
    for (int r = 0; r < 8; ++r) acc[r] = 0.0;
    dot8_a<32>(hRd + Hc * Bc + (kg * 32) * Bc + b, &wl1[Hc + kg * 32], 1024, acc);

    bar_wait(flags, ep);   // h0[t] now visible

    // ---- phase c: L1 dependent part ----
    dot8_a<32>(hWr + (kg * 32) * Bc + b, &wl1[kg * 32], 1024, acc);
    write_plane(pbuf, acc, kg, b);
    __syncthreads();
    if (tid < 128) {
      float hn = lstm_cell(pbuf, biasesD[1], cu * 4, b, &c1r);
      stg1(&hWr[Hc * Bc + (j0 + cu) * Bc + b], hn);
    }
    bar_signal(flags, ++ep);

    // ---- phase d (hidden behind barrier): precompute L0[t+1] indep parts ----
#pragma unroll
    for (int r = 0; r < 8; ++r) accL0[r] = 0.0;
    if (t + 1 < Tc) {
      if (!upn)
        dot8_x<16>(x + ((size_t)b * Tc + (t + 1)) * NINc + kg * 16, &wl0[kg * 16], 768, accL0);
      dot8_a<32>(hWr + (kg * 32) * Bc + b, &wl0[NINc + kg * 32], 768, accL0); // W_hh0 @ h0[t]
    }

    bar_wait(flags, ep);   // h1[t] now visible

    // ---- phase e: head (row n = blk) ----
    {
      const float* Ah = hWr + Hc * Bc + (kg * 32) * Bc + b;
      float av[32];
#pragma unroll
      for (int k = 0; k < 32; ++k) av[k] = ldg1(Ah + k * Bc);
      double hs = 0.0;
#pragma unroll
      for (int kk = 0; kk < 32; kk += 4) {
        float4 w = *(const float4*)(&whd[kg * 32] + kk);
        float pp =  av[kk + 0] * w.x;
        pp = fmaf(av[kk + 1], w.y, pp);
        pp = fmaf(av[kk + 2], w.z, pp);
        pp = fmaf(av[kk + 3], w.w, pp);
        hs += (double)pp;
      }
      pbuf[kg * 64 + b] = (float)hs;
    }
    __syncthreads();
    if (tid < 64) {
      double s = bembs;
#pragma unroll
      for (int pl = 0; pl < NWAVE; ++pl) s += (double)pbuf[pl * 64 + b];
      float o = (float)tanh(s);
      stg1(&outT[blk * Bc + b], o);                    // feedback buffer [NOUT][B]
      out[((size_t)b * Tc + t) * NOUTc + blk] = o;     // final output [B,T,NOUT]
    }
    if (upn) {
      bar_signal(flags, ++ep);   // publish out[t]
      bar_wait(flags, ep);
    } else if (t + 1 < Tc) {
      __syncthreads();           // pbuf reuse guard
    }
  }
}

extern "C" void kernel_launch(void* const* d_in, const int* in_sizes, int n_in,
                              void* d_out, int out_size, void* d_ws, size_t ws_size,
                              hipStream_t stream) {
  const float* x    = (const float*)d_in[0];
  const float* h0   = (const float*)d_in[1];
  const float* c0   = (const float*)d_in[2];
  const float* Wih0 = (const float*)d_in[3];
  const float* Wih1 = (const float*)d_in[4];
  const float* Whh  = (const float*)d_in[5];
  const float* bih  = (const float*)d_in[6];
  const float* bhh  = (const float*)d_in[7];
  const float* Wemb = (const float*)d_in[8];
  const float* bemb = (const float*)d_in[9];
  const unsigned char* uprev = (const unsigned char*)d_in[10];
  float* out = (float*)d_out;
  float* ws  = (float*)d_ws;

  // zero the flag array (first 1 KiB of ws) every call (inside graph → every replay)
  hipMemsetAsync(d_ws, 0, 1024, stream);

  void* args[] = {(void*)&x, (void*)&h0, (void*)&c0, (void*)&Wih0, (void*)&Wih1,
                  (void*)&Whh, (void*)&bih, (void*)&bhh, (void*)&Wemb, (void*)&bemb,
                  (void*)&uprev, (void*)&out, (void*)&ws};
  hipLaunchCooperativeKernel((void*)lstm_seq_kernel, dim3(NBLK), dim3(NTHR),
                             args, 0, stream);
}

// Round 6
// 40093.912 us; speedup vs baseline: 1.4576x; 1.3329x over previous
//
#include <hip/hip_runtime.h>

// Problem constants
#define Bc   64
#define Tc   512
#define NINc 256
#define Hc   512
#define NOUTc 256
#define NBLK 256
#define NTHR 1024
#define NWAVE 16

__device__ __forceinline__ double dsig(double x) { return 1.0 / (1.0 + exp(-x)); }

// ---- agent-coherent scalar store (bypass L1/L2, land at coherence point) ----
__device__ __forceinline__ void stg1(float* p, float v) {
  __hip_atomic_store(p, v, __ATOMIC_RELAXED, __HIP_MEMORY_SCOPE_AGENT);
}

// ---- flag-array grid barrier ----
// signal: __syncthreads() drains vmcnt(0) per wave (all sc1 h-stores ACKed at the
// coherence point) before tid0's relaxed flag store issues. No wbl2.
__device__ __forceinline__ void bar_signal(unsigned* __restrict__ flags, unsigned ep) {
  __syncthreads();
  asm volatile("" ::: "memory");
  if (threadIdx.x == 0)
    __hip_atomic_store(&flags[blockIdx.x], ep, __ATOMIC_RELAXED, __HIP_MEMORY_SCOPE_AGENT);
}
// wait: wave 0 polls all flags (sc1 reads), then ONE acquire fence (buffer_inv)
// for the whole block — normal cached loads afterwards refetch fresh data.
__device__ __forceinline__ void bar_wait(unsigned* __restrict__ flags, unsigned ep) {
  if (threadIdx.x < 64) {
    for (;;) {
      bool ok = true;
#pragma unroll
      for (int i = 0; i < NBLK / 64; ++i) {
        unsigned v = __hip_atomic_load(&flags[threadIdx.x + i * 64], __ATOMIC_RELAXED,
                                       __HIP_MEMORY_SCOPE_AGENT);
        ok &= (v >= ep);
      }
      if (__all(ok)) break;
      __builtin_amdgcn_s_sleep(2);
    }
    __builtin_amdgcn_fence(__ATOMIC_ACQUIRE, "agent");  // single buffer_inv per block
  }
  __syncthreads();
  asm volatile("" ::: "memory");
}

// ---- 8-row dot chunk, A strided by Bc (activations, NORMAL cached loads) ----
// mixed precision: 4-term f32 fma groups summed into f64 accumulators
template<int NK>
__device__ __forceinline__ void dot8_a(const float* __restrict__ A,
                                       const float* __restrict__ W,
                                       const int wstride,
                                       double* __restrict__ acc) {
  float av[NK];
#pragma unroll
  for (int k = 0; k < NK; ++k) av[k] = A[k * Bc];
#pragma unroll
  for (int kk = 0; kk < NK; kk += 4) {
#pragma unroll
    for (int r = 0; r < 8; ++r) {
      float4 w = *(const float4*)(W + r * wstride + kk);
      float p =  av[kk + 0] * w.x;
      p = fmaf(av[kk + 1], w.y, p);
      p = fmaf(av[kk + 2], w.z, p);
      p = fmaf(av[kk + 3], w.w, p);
      acc[r] += (double)p;
    }
  }
}

// Same but A contiguous (raw x row, cached)
template<int NK>
__device__ __forceinline__ void dot8_x(const float* __restrict__ A,
                                       const float* __restrict__ W,
                                       const int wstride,
                                       double* __restrict__ acc) {
#pragma unroll
  for (int kk = 0; kk < NK; kk += 4) {
    float4 av = *(const float4*)(A + kk);
#pragma unroll
    for (int r = 0; r < 8; ++r) {
      float4 w = *(const float4*)(W + r * wstride + kk);
      float p =  av.x * w.x;
      p = fmaf(av.y, w.y, p);
      p = fmaf(av.z, w.z, p);
      p = fmaf(av.w, w.w, p);
      acc[r] += (double)p;
    }
  }
}

__device__ __forceinline__ void write_plane(float* __restrict__ pb,
                                            const double* __restrict__ acc,
                                            int kg, int b) {
#pragma unroll
  for (int r = 0; r < 8; ++r) pb[(kg * 8 + r) * 64 + b] = (float)acc[r];
}

__device__ __forceinline__ double sum_planes(const float* __restrict__ pb,
                                             int r, int b) {
  double s = 0.0;
#pragma unroll
  for (int p = 0; p < NWAVE; ++p) s += (double)pb[(p * 8 + r) * 64 + b];
  return s;
}

__device__ __forceinline__ float lstm_cell(const float* __restrict__ pb,
                                           const double* __restrict__ bias,
                                           int r0, int b, double* c) {
  double gi = sum_planes(pb, r0 + 0, b) + bias[r0 + 0];
  double gf = sum_planes(pb, r0 + 1, b) + bias[r0 + 1];
  double gg = sum_planes(pb, r0 + 2, b) + bias[r0 + 2];
  double go = sum_planes(pb, r0 + 3, b) + bias[r0 + 3];
  double cn = dsig(gf) * (*c) + dsig(gi) * tanh(gg);
  *c = cn;
  return (float)(dsig(go) * tanh(cn));
}

extern "C" __global__ __launch_bounds__(NTHR, 1)
void lstm_seq_kernel(const float* __restrict__ x,      // [B,T,NIN]
                     const float* __restrict__ h0in,   // [L,B,H]
                     const float* __restrict__ c0in,   // [L,B,H]
                     const float* __restrict__ Wih0,   // [4H,NIN]
                     const float* __restrict__ Wih1,   // [4H,H]
                     const float* __restrict__ Whh,    // [L,4H,H]
                     const float* __restrict__ bih,    // [L,4H]
                     const float* __restrict__ bhh,    // [L,4H]
                     const float* __restrict__ Wemb,   // [NOUT,H]
                     const float* __restrict__ bemb,   // [NOUT]
                     const unsigned char* __restrict__ uprev, // [T] bool (or int32)
                     float* __restrict__ out,          // [B,T,NOUT]
                     float* __restrict__ ws) {
  __shared__ __align__(16) float wl0[8 * 768];    // [r][ W_ih0(256) | W_hh0(512) ]
  __shared__ __align__(16) float wl1[8 * 1024];   // [r][ W_ih1(512) | W_hh1(512) ]
  __shared__ __align__(16) float whd[512];        // W_emb row `blk`
  __shared__ __align__(16) float pbuf[NWAVE * 8 * 64];
  __shared__ double biasesD[2][8];
  __shared__ double bembs;
  __shared__ int up_mode;

  const int tid = threadIdx.x;
  const int blk = blockIdx.x;
  const int b   = tid & 63;
  const int kg  = tid >> 6;   // wave index = K-group (0..15)
  const int j0  = blk * 2;

  unsigned* flags = (unsigned*)ws;             // 256 u32, zeroed by host memset
  float* hbuf = ws + 256;                      // [2 parity][L][H][B]
  float* outT = hbuf + 2 * 2 * Hc * Bc;        // [NOUT][B]

  // ---- detect use_prev dtype ----
  if (tid == 0) up_mode = 1;
  __syncthreads();
  {
    int bad = 0;
    for (int idx = tid; idx < Tc; idx += NTHR)
      if ((idx & 3) && uprev[idx]) bad = 1;
    if (bad) up_mode = 0;
  }

  // ---- load weights into LDS (cached reads) ----
  for (int r = 0; r < 8; ++r) {
    const int u = r >> 2, g = r & 3;
    const int row = g * Hc + (j0 + u);
    const float* sA = Wih0 + (size_t)row * NINc;
    const float* sB = Whh  + (size_t)row * Hc;
    const float* sC = Wih1 + (size_t)row * Hc;
    const float* sD = Whh  + (size_t)(4 * Hc) * Hc + (size_t)row * Hc;
    for (int i = tid; i < NINc; i += NTHR) wl0[r * 768 + i] = sA[i];
    for (int i = tid; i < Hc;   i += NTHR) wl0[r * 768 + NINc + i] = sB[i];
    for (int i = tid; i < Hc;   i += NTHR) wl1[r * 1024 + i] = sC[i];
    for (int i = tid; i < Hc;   i += NTHR) wl1[r * 1024 + Hc + i] = sD[i];
    if (tid == 0) {
      biasesD[0][r] = (double)bih[row] + (double)bhh[row];
      biasesD[1][r] = (double)bih[4 * Hc + row] + (double)bhh[4 * Hc + row];
    }
  }
  for (int i = tid; i < Hc; i += NTHR) whd[i] = Wemb[(size_t)blk * Hc + i];
  if (tid == 0) bembs = (double)bemb[blk];

  // ---- init h (parity 0) transposed to [L][H][B]; sc1 stores ----
  for (int idx = blk * NTHR + tid; idx < 2 * Hc * Bc; idx += NBLK * NTHR) {
    const int l   = idx / (Hc * Bc);
    const int rem = idx - l * (Hc * Bc);
    const int j   = rem >> 6;
    const int bb  = rem & 63;
    stg1(&hbuf[idx], h0in[((size_t)l * Bc + bb) * Hc + j]);
  }

  // ---- cell state (f64) in registers of threads 0..127 ----
  double c0r = 0.0, c1r = 0.0;
  const int cu = tid >> 6;
  if (tid < 128) {
    const int j = j0 + cu;
    c0r = (double)c0in[((size_t)0 * Bc + b) * Hc + j];
    c1r = (double)c0in[((size_t)1 * Bc + b) * Hc + j];
  }
  __syncthreads();
  const int upm = up_mode;
  const int* uprev32 = (const int*)uprev;
#define UPAT(tt) (upm ? (uprev32[tt] != 0) : (uprev[tt] != 0))

  unsigned ep = 0;
  bar_signal(flags, ++ep);
  bar_wait(flags, ep);

  // ---- pre-loop: L0[0] pre-activation (up[0] is false by construction) ----
  double accL0[8];
#pragma unroll
  for (int r = 0; r < 8; ++r) accL0[r] = 0.0;
  dot8_x<16>(x + ((size_t)b * Tc + 0) * NINc + kg * 16, &wl0[kg * 16], 768, accL0);
  dot8_a<32>(hbuf + (kg * 32) * Bc + b, &wl0[NINc + kg * 32], 768, accL0);

  for (int t = 0; t < Tc; ++t) {
    const int p = t & 1;
    const float* hRd = hbuf + p * (2 * Hc * Bc);
    float* hWr = hbuf + (p ^ 1) * (2 * Hc * Bc);
    const bool upn = (t + 1 < Tc) && UPAT(t + 1);

    // ---- phase a: finish L0[t] (out-part only when feedback) ----
    if (t > 0 && UPAT(t))
      dot8_a<16>(outT + (kg * 16) * Bc + b, &wl0[kg * 16], 768, accL0);
    write_plane(pbuf, accL0, kg, b);
    __syncthreads();
    if (tid < 128) {
      float hn = lstm_cell(pbuf, biasesD[0], cu * 4, b, &c0r);
      stg1(&hWr[(j0 + cu) * Bc + b], hn);
    }
    bar_signal(flags, ++ep);

    // ---- phase b (hidden behind barrier): L1 recurrent part, h1[t-1] (cached) ----
    double acc[8];
#pragma unroll
    for (int r = 0; r < 8; ++r) acc[r] = 0.0;
    dot8_a<32>(hRd + Hc * Bc + (kg * 32) * Bc + b, &wl1[Hc + kg * 32], 1024, acc);

    bar_wait(flags, ep);   // h0[t] now visible (L1/L2 invalidated once)

    // ---- phase c: L1 dependent part ----
    dot8_a<32>(hWr + (kg * 32) * Bc + b, &wl1[kg * 32], 1024, acc);
    write_plane(pbuf, acc, kg, b);
    __syncthreads();
    if (tid < 128) {
      float hn = lstm_cell(pbuf, biasesD[1], cu * 4, b, &c1r);
      stg1(&hWr[Hc * Bc + (j0 + cu) * Bc + b], hn);
    }
    bar_signal(flags, ++ep);

    // ---- phase d (hidden behind barrier): precompute L0[t+1] indep parts ----
#pragma unroll
    for (int r = 0; r < 8; ++r) accL0[r] = 0.0;
    if (t + 1 < Tc) {
      if (!upn)
        dot8_x<16>(x + ((size_t)b * Tc + (t + 1)) * NINc + kg * 16, &wl0[kg * 16], 768, accL0);
      dot8_a<32>(hWr + (kg * 32) * Bc + b, &wl0[NINc + kg * 32], 768, accL0); // W_hh0 @ h0[t]
    }

    bar_wait(flags, ep);   // h1[t] now visible

    // ---- phase e: head (row n = blk) ----
    {
      const float* Ah = hWr + Hc * Bc + (kg * 32) * Bc + b;
      float av[32];
#pragma unroll
      for (int k = 0; k < 32; ++k) av[k] = Ah[k * Bc];
      double hs = 0.0;
#pragma unroll
      for (int kk = 0; kk < 32; kk += 4) {
        float4 w = *(const float4*)(&whd[kg * 32] + kk);
        float pp =  av[kk + 0] * w.x;
        pp = fmaf(av[kk + 1], w.y, pp);
        pp = fmaf(av[kk + 2], w.z, pp);
        pp = fmaf(av[kk + 3], w.w, pp);
        hs += (double)pp;
      }
      pbuf[kg * 64 + b] = (float)hs;
    }
    __syncthreads();
    if (tid < 64) {
      double s = bembs;
#pragma unroll
      for (int pl = 0; pl < NWAVE; ++pl) s += (double)pbuf[pl * 64 + b];
      float o = (float)tanh(s);
      stg1(&outT[blk * Bc + b], o);                    // feedback buffer [NOUT][B]
      out[((size_t)b * Tc + t) * NOUTc + blk] = o;     // final output [B,T,NOUT]
    }
    if (upn) {
      bar_signal(flags, ++ep);   // publish out[t]
      bar_wait(flags, ep);
    } else if (t + 1 < Tc) {
      __syncthreads();           // pbuf reuse guard
    }
  }
}

extern "C" void kernel_launch(void* const* d_in, const int* in_sizes, int n_in,
                              void* d_out, int out_size, void* d_ws, size_t ws_size,
                              hipStream_t stream) {
  const float* x    = (const float*)d_in[0];
  const float* h0   = (const float*)d_in[1];
  const float* c0   = (const float*)d_in[2];
  const float* Wih0 = (const float*)d_in[3];
  const float* Wih1 = (const float*)d_in[4];
  const float* Whh  = (const float*)d_in[5];
  const float* bih  = (const float*)d_in[6];
  const float* bhh  = (const float*)d_in[7];
  const float* Wemb = (const float*)d_in[8];
  const float* bemb = (const float*)d_in[9];
  const unsigned char* uprev = (const unsigned char*)d_in[10];
  float* out = (float*)d_out;
  float* ws  = (float*)d_ws;

  // zero the flag array (first 1 KiB of ws) every call (inside graph → every replay)
  hipMemsetAsync(d_ws, 0, 1024, stream);

  void* args[] = {(void*)&x, (void*)&h0, (void*)&c0, (void*)&Wih0, (void*)&Wih1,
                  (void*)&Whh, (void*)&bih, (void*)&bhh, (void*)&Wemb, (void*)&bemb,
                  (void*)&uprev, (void*)&out, (void*)&ws};
  hipLaunchCooperativeKernel((void*)lstm_seq_kernel, dim3(NBLK), dim3(NTHR),
                             args, 0, stream);
}